// Round 1
// baseline (220.097 us; speedup 1.0000x reference)
//
#include <hip/hip_runtime.h>
#include <hip/hip_bf16.h>

typedef unsigned short u16;
typedef unsigned int   u32;

#define BATCH 4096
#define IDIM  1024
#define ODIM  1024
#define NDEG  9                 // degree 8 -> 9 basis terms
#define KTOT  (IDIM * NDEG)     // 9216

#define BM 128
#define BN 128
#define BKK 64

typedef __attribute__((ext_vector_type(8))) short short8_t;   // 8 bf16 = 4 VGPRs
typedef __attribute__((ext_vector_type(4))) float f32x4;

// round-to-nearest-even f32 -> bf16 (values are finite; no NaN handling needed)
__device__ __forceinline__ u16 f2bf(float f) {
    union { float f; u32 u; } v; v.f = f;
    u32 r = v.u + 0x7FFFu + ((v.u >> 16) & 1u);
    return (u16)(r >> 16);
}
__device__ __forceinline__ u32 pack2bf(float lo, float hi) {
    return (u32)f2bf(lo) | ((u32)f2bf(hi) << 16);
}

// async 16B global -> LDS (hardware: wave-uniform base + lane*16)
__device__ __forceinline__ void gl_lds16(const u16* g, u16* l) {
    __builtin_amdgcn_global_load_lds(
        (const __attribute__((address_space(1))) void*)g,
        (__attribute__((address_space(3))) void*)l,
        16, 0, 0);
}

// ---------------------------------------------------------------------------
// A[b][k] bf16, k = d*1024 + i :  A = V_d(tanh(x[b,i]))
// thread handles 2 consecutive i -> packed u32 stores (coalesced per d)
// ---------------------------------------------------------------------------
__global__ void prep_a_kernel(const float* __restrict__ x, u16* __restrict__ A) {
    int t  = blockIdx.x * 256 + threadIdx.x;      // over BATCH*IDIM/2
    int b  = t >> 9;
    int i2 = (t & 511) << 1;
    float2 xv = ((const float2*)x)[t];
    float t0 = tanhf(xv.x), t1 = tanhf(xv.y);
    u32* dst = (u32*)(A + (size_t)b * KTOT + i2); // d-stride = 1024 u16 = 512 u32
    float a0 = 2.0f, a1 = 2.0f;                   // V0
    float b0 = t0,  b1 = t1;                      // V1
    dst[0]   = pack2bf(2.0f, 2.0f);
    dst[512] = pack2bf(t0, t1);
#pragma unroll
    for (int d = 2; d < NDEG; ++d) {
        float n0 = t0 * b0 + a0;
        float n1 = t1 * b1 + a1;
        dst[(size_t)d * 512] = pack2bf(n0, n1);
        a0 = b0; b0 = n0; a1 = b1; b1 = n1;
    }
}

// ---------------------------------------------------------------------------
// Bt[o][k] bf16, k = d*1024 + i :  Bt = coeffs[i][o][d]   (coeffs d-fastest)
// lanes over i -> writes coalesced; reads line-underutilized (round-2 target)
// ---------------------------------------------------------------------------
__global__ void prep_b_kernel(const float* __restrict__ c, u16* __restrict__ Bt) {
    int t = blockIdx.x * 256 + threadIdx.x;       // over ODIM*IDIM
    int o = t >> 10;
    int i = t & 1023;
    const float* src = c + ((size_t)i * ODIM + o) * NDEG;
    u16* dst = Bt + (size_t)o * KTOT + i;
#pragma unroll
    for (int d = 0; d < NDEG; ++d)
        dst[(size_t)d * 1024] = f2bf(src[d]);
}

// ---------------------------------------------------------------------------
// GEMM: C[m][n] += A[m][k] * Bt[n][k], 128x128 tile, BK=64, 4 waves of 64x64.
// LDS layout: tile as [row][8 chunks of 16B], physical chunk = c ^ (row&7)
// -> global_load_lds staging (lane L of a wave-slab sources chunk (L&7)^(L>>3))
// -> ds_read_b128 frag reads land 2 lanes/bank (free).
// ---------------------------------------------------------------------------
__global__ __launch_bounds__(256, 2)
void gemm_kernel(const u16* __restrict__ A, const u16* __restrict__ B,
                 float* __restrict__ C, int kLen) {
    __shared__ __align__(16) u16 ldsA[BM * BKK];  // 16 KB
    __shared__ __align__(16) u16 ldsB[BN * BKK];  // 16 KB

    const int tid  = threadIdx.x;
    const int lane = tid & 63;
    const int wave = tid >> 6;
    const int quad = lane >> 4;
    const int l15  = lane & 15;
    const int wm   = wave & 1;
    const int wn   = wave >> 1;
    const int bm   = blockIdx.y;
    const int bn   = blockIdx.x;
    const int kStart = blockIdx.z * kLen;
    C += (size_t)blockIdx.z * BATCH * ODIM;

    const u16* ga[4]; const u16* gb[4];
    u16* la[4]; u16* lb[4];
#pragma unroll
    for (int t = 0; t < 4; ++t) {
        int s  = t * 256 + tid;                   // 16B slot in tile, 0..1023
        int r  = s >> 3;                          // tile row 0..127
        int sc = (s & 7) ^ (r & 7);               // source k-chunk (XOR swizzle)
        ga[t] = A + (size_t)(bm * BM + r) * KTOT + kStart + sc * 8;
        gb[t] = B + (size_t)(bn * BN + r) * KTOT + kStart + sc * 8;
        la[t] = ldsA + s * 8;
        lb[t] = ldsB + s * 8;
    }

    f32x4 acc[4][4];
#pragma unroll
    for (int mt = 0; mt < 4; ++mt)
#pragma unroll
        for (int nt = 0; nt < 4; ++nt)
            acc[mt][nt] = (f32x4){0.f, 0.f, 0.f, 0.f};

    const int nIter = kLen / BKK;
    for (int it = 0; it < nIter; ++it) {
#pragma unroll
        for (int t = 0; t < 4; ++t) gl_lds16(ga[t], la[t]);
#pragma unroll
        for (int t = 0; t < 4; ++t) gl_lds16(gb[t], lb[t]);
        __syncthreads();

#pragma unroll
        for (int kk = 0; kk < 2; ++kk) {
            short8_t af[4], bfg[4];
#pragma unroll
            for (int mt = 0; mt < 4; ++mt) {
                int row = wm * 64 + mt * 16 + l15;
                int pc  = (kk * 4 + quad) ^ (row & 7);
                af[mt] = *(const short8_t*)(ldsA + (row * 8 + pc) * 8);
            }
#pragma unroll
            for (int nt = 0; nt < 4; ++nt) {
                int row = wn * 64 + nt * 16 + l15;
                int pc  = (kk * 4 + quad) ^ (row & 7);
                bfg[nt] = *(const short8_t*)(ldsB + (row * 8 + pc) * 8);
            }
#pragma unroll
            for (int mt = 0; mt < 4; ++mt)
#pragma unroll
                for (int nt = 0; nt < 4; ++nt)
                    acc[mt][nt] = __builtin_amdgcn_mfma_f32_16x16x32_bf16(
                        af[mt], bfg[nt], acc[mt][nt], 0, 0, 0);
        }
        __syncthreads();

#pragma unroll
        for (int t = 0; t < 4; ++t) { ga[t] += BKK; gb[t] += BKK; }
    }

    // epilogue: C/D layout col = lane&15, row = quad*4 + reg  [m89-verified]
#pragma unroll
    for (int mt = 0; mt < 4; ++mt) {
#pragma unroll
        for (int nt = 0; nt < 4; ++nt) {
            int row0 = bm * BM + wm * 64 + mt * 16 + quad * 4;
            int col  = bn * BN + wn * 64 + nt * 16 + l15;
#pragma unroll
            for (int r = 0; r < 4; ++r)
                C[(size_t)(row0 + r) * ODIM + col] = acc[mt][nt][r];
        }
    }
}

// out = P[0] + P[1]  (split-K reduction), float4 vectorized
__global__ void reduce_kernel(const float* __restrict__ P, float* __restrict__ out) {
    int t = blockIdx.x * 256 + threadIdx.x;       // over BATCH*ODIM/4
    f32x4 a = ((const f32x4*)P)[t];
    f32x4 b = ((const f32x4*)(P + (size_t)BATCH * ODIM))[t];
    ((f32x4*)out)[t] = a + b;
}

extern "C" void kernel_launch(void* const* d_in, const int* in_sizes, int n_in,
                              void* d_out, int out_size, void* d_ws, size_t ws_size,
                              hipStream_t stream) {
    const float* x      = (const float*)d_in[0];   // [4096,1024] f32
    const float* coeffs = (const float*)d_in[1];   // [1024,1024,9] f32
    float* out = (float*)d_out;                    // [4096,1024] f32

    u16* A  = (u16*)d_ws;                          // 75.5 MB
    u16* Bt = A + (size_t)BATCH * KTOT;            // 18.9 MB
    float* P = (float*)(Bt + (size_t)ODIM * KTOT); // 33.5 MB (split-K partials)

    size_t need_base  = ((size_t)BATCH * KTOT + (size_t)ODIM * KTOT) * 2;
    size_t need_split = need_base + (size_t)2 * BATCH * ODIM * 4;

    prep_a_kernel<<<BATCH * IDIM / 512, 256, 0, stream>>>(x, A);
    prep_b_kernel<<<ODIM * IDIM / 256, 256, 0, stream>>>(coeffs, Bt);

    if (ws_size >= need_split) {
        // split-K=2: 512 blocks -> 2 blocks/CU for barrier-drain overlap
        dim3 grid(ODIM / BN, BATCH / BM, 2);
        gemm_kernel<<<grid, 256, 0, stream>>>(A, Bt, P, KTOT / 2);
        reduce_kernel<<<BATCH * ODIM / 1024, 256, 0, stream>>>(P, out);
    } else {
        dim3 grid(ODIM / BN, BATCH / BM, 1);
        gemm_kernel<<<grid, 256, 0, stream>>>(A, Bt, out, KTOT);
    }
}